// Round 1
// baseline (158.189 us; speedup 1.0000x reference)
//
#include <hip/hip_runtime.h>
#include <hip/hip_bf16.h>

// ---------------- problem constants ----------------
#define CHW   1048576        // 256*64*64
#define PH    66             // padded H/W
// ws layout (bytes)
#define XQ_BYTES 35684352u   // 16*66*66*256*2
#define WQ_OFF   35684352u   // 9*256*256*2 = 1179648
#define GNP_OFF  36864000u   // double2[1024]
#define MR_OFF   36880384u   // float2[16]
#define GP_OFF   36880512u   // float[1024]
#define SC_OFF   36884608u   // float[4]: gamma, 128/gamma, qscale
#define WP_OFF   36884640u   // double[36]
#define DL_OFF   36884928u   // float delta

typedef __attribute__((ext_vector_type(8)))  short short8;
typedef __attribute__((ext_vector_type(16))) float f32x16;

__device__ __forceinline__ unsigned short f2bf(float f) {
    __hip_bfloat16 h = __float2bfloat16(f);
    return __builtin_bit_cast(unsigned short, h);
}

// ---------- K1a: per-sample partial sum/sumsq (grid 16*64, block 256) ----------
__global__ void k_gn_part(const float* __restrict__ x, double2* __restrict__ part) {
    int blk = blockIdx.x;
    int n = blk >> 6, b = blk & 63;
    int t = threadIdx.x;
    const float4* p = (const float4*)(x + (size_t)n * CHW + (size_t)b * 16384);
    double s = 0.0, ss = 0.0;
#pragma unroll
    for (int j = 0; j < 16; ++j) {
        float4 v = p[j * 256 + t];
        double dx = v.x, dy = v.y, dz = v.z, dw = v.w;
        s  += dx + dy + dz + dw;
        ss += dx * dx + dy * dy + dz * dz + dw * dw;
    }
    for (int o = 32; o; o >>= 1) { s += __shfl_down(s, o); ss += __shfl_down(ss, o); }
    __shared__ double sh0[4], sh1[4];
    if ((t & 63) == 0) { sh0[t >> 6] = s; sh1[t >> 6] = ss; }
    __syncthreads();
    if (t == 0)
        part[blk] = make_double2(sh0[0] + sh0[1] + sh0[2] + sh0[3],
                                 sh1[0] + sh1[1] + sh1[2] + sh1[3]);
}

// ---------- K1b: finalize mean/rstd (grid 16, block 64) ----------
__global__ void k_gn_final(const double2* __restrict__ part, float2* __restrict__ mr) {
    int n = blockIdx.x, t = threadIdx.x;
    double2 v = part[n * 64 + t];
    double s = v.x, ss = v.y;
    for (int o = 32; o; o >>= 1) { s += __shfl_down(s, o); ss += __shfl_down(ss, o); }
    if (t == 0) {
        double mean = s * (1.0 / 1048576.0);
        double var  = ss * (1.0 / 1048576.0) - mean * mean;
        mr[n] = make_float2((float)mean, (float)(1.0 / sqrt(var + 1e-5)));
    }
}

// ---------- K2a: partial absmax of x_ln (grid 16*64, block 256) ----------
__global__ void k_absmax(const float* __restrict__ x, const float2* __restrict__ mr,
                         const float* __restrict__ lnw, const float* __restrict__ lnb,
                         float* __restrict__ gp) {
    int blk = blockIdx.x;
    int n = blk >> 6, b = blk & 63;
    int t = threadIdx.x;
    float2 m = mr[n];
    const float* xb = x + (size_t)n * CHW + (size_t)b * 16384;
    float mx = 0.0f;
#pragma unroll
    for (int j = 0; j < 16; ++j) {
        int c = b * 4 + (j >> 2);            // uniform per iteration
        float g = lnw[c] * m.y;              // rstd * gamma_c
        float be = lnb[c];
        float4 v = *(const float4*)(xb + j * 1024 + t * 4);
        mx = fmaxf(mx, fabsf((v.x - m.x) * g + be));
        mx = fmaxf(mx, fabsf((v.y - m.x) * g + be));
        mx = fmaxf(mx, fabsf((v.z - m.x) * g + be));
        mx = fmaxf(mx, fabsf((v.w - m.x) * g + be));
    }
    for (int o = 32; o; o >>= 1) mx = fmaxf(mx, __shfl_down(mx, o));
    __shared__ float sh[4];
    if ((t & 63) == 0) sh[t >> 6] = mx;
    __syncthreads();
    if (t == 0) gp[blk] = fmaxf(fmaxf(sh[0], sh[1]), fmaxf(sh[2], sh[3]));
}

// ---------- K2b: gamma + scales (grid 1, block 256) ----------
__global__ void k_gamma(const float* __restrict__ gp, float* __restrict__ sc) {
    int t = threadIdx.x;
    float m = 0.0f;
#pragma unroll
    for (int j = 0; j < 4; ++j) m = fmaxf(m, gp[t + j * 256]);
    for (int o = 32; o; o >>= 1) m = fmaxf(m, __shfl_down(m, o));
    __shared__ float sh[4];
    if ((t & 63) == 0) sh[t >> 6] = m;
    __syncthreads();
    if (t == 0) {
        float gamma = fmaxf(fmaxf(fmaxf(sh[0], sh[1]), fmaxf(sh[2], sh[3])), 1e-6f);
        sc[0] = gamma;
        sc[1] = 128.0f / gamma;
        sc[2] = (gamma / 128.0f) * 0.01f;    // dequant * SCALE
    }
}

// ---------- K3a: partial sum |W| (grid 36, block 256) ----------
__global__ void k_wsum(const float* __restrict__ w, double* __restrict__ wp) {
    int blk = blockIdx.x, t = threadIdx.x;
    const float4* p = (const float4*)(w + (size_t)blk * 16384);
    double s = 0.0;
#pragma unroll
    for (int j = 0; j < 16; ++j) {
        float4 v = p[j * 256 + t];
        s += fabs((double)v.x) + fabs((double)v.y) + fabs((double)v.z) + fabs((double)v.w);
    }
    for (int o = 32; o; o >>= 1) s += __shfl_down(s, o);
    __shared__ double sh[4];
    if ((t & 63) == 0) sh[t >> 6] = s;
    __syncthreads();
    if (t == 0) wp[blk] = sh[0] + sh[1] + sh[2] + sh[3];
}

// ---------- K3b: delta (grid 1, block 64) ----------
__global__ void k_wdelta(const double* __restrict__ wp, float* __restrict__ dl) {
    int t = threadIdx.x;
    double s = (t < 36) ? wp[t] : 0.0;
    for (int o = 32; o; o >>= 1) s += __shfl_down(s, o);
    if (t == 0) dl[0] = (float)(0.7 * (s / 589824.0));
}

// ---------- K3c: ternary quantize W -> wq[tap][co][ci] bf16 sign (grid 2304, block 256) ----------
__global__ void k_wquant(const float* __restrict__ w, const float* __restrict__ dl,
                         unsigned short* __restrict__ wq) {
    int o = blockIdx.x * 256 + threadIdx.x;   // tap*65536 + co*256 + ci
    int tap = o >> 16, rem = o & 65535, co = rem >> 8, ci = rem & 255;
    float d = dl[0];
    float v = w[co * 2304 + ci * 9 + tap];
    float s = (v > d) ? 1.0f : ((v < -d) ? -1.0f : 0.0f);
    wq[o] = f2bf(s);
}

// ---------- K4: GN + quantize + NCHW -> padded NHWC bf16 (grid 1024, block 256) ----------
__global__ void k_quantx(const float* __restrict__ x, const float2* __restrict__ mr,
                         const float* __restrict__ sc, const float* __restrict__ lnw,
                         const float* __restrict__ lnb, unsigned short* __restrict__ xq) {
    int bid = blockIdx.x;
    int n = bid >> 6, hg = (bid >> 2) & 15, cg = bid & 3;
    int t = threadIdx.x;
    int w = t & 63, h = hg * 4 + (t >> 6);
    float2 m = mr[n];
    float s128 = sc[1];
    uint q[32];
    const float* xp = x + (((size_t)n * 256 + cg * 64) * 64 + h) * 64 + w;
#pragma unroll
    for (int ci = 0; ci < 64; ++ci) {
        int c = cg * 64 + ci;
        float g = lnw[c] * m.y;
        float be = lnb[c];
        float v = xp[(size_t)ci * 4096];
        float xs = ((v - m.x) * g + be) * s128;
        xs = fminf(fmaxf(xs, -(128.0f - 1e-6f)), (128.0f - 1e-6f));
        unsigned short ub = f2bf(rintf(xs));
        if (ci & 1) q[ci >> 1] |= ((uint)ub << 16);
        else        q[ci >> 1]  = ub;
    }
    unsigned short* op = xq + ((size_t)(n * 66 + h + 1) * 66 + (w + 1)) * 256 + cg * 64;
    uint4* o4 = (uint4*)op;
#pragma unroll
    for (int s2 = 0; s2 < 8; ++s2)
        o4[s2] = make_uint4(q[s2 * 4], q[s2 * 4 + 1], q[s2 * 4 + 2], q[s2 * 4 + 3]);
}

// ---------- K5: conv as 9-tap implicit GEMM, bf16 MFMA 32x32x16 ----------
// block: 512 thr (8 waves, 2m x 4n), tile BM=128 (n, 2 h-rows) x BN=256 co, K-stage = 64 ci
__global__ __launch_bounds__(512) void k_conv(const unsigned short* __restrict__ xq,
                                              const unsigned short* __restrict__ wq,
                                              const float* __restrict__ sc,
                                              const float* __restrict__ bias,
                                              float* __restrict__ out) {
    __shared__ unsigned short lA[128 * 64];   // 16 KB: [row m][64 ci], 128B rows, xor-swizzled
    __shared__ unsigned short lB[256 * 64];   // 32 KB: [row co][64 ci]
    int bid = blockIdx.x;
    int n = bid >> 5, h0 = (bid & 31) << 1;
    int t = threadIdx.x, wv = t >> 6, l = t & 63;
    int wm = wv >> 2, wn = wv & 3;
    int l31 = l & 31, l5 = l >> 5;

    // staging assignment: A row = t/4 (2x16B slots), B row = t/2 (4x16B slots)
    int ra = t >> 2, sa = (t & 3) * 2;
    int rb = t >> 1, sb = (t & 1) * 4;
    int ha = h0 + (ra >> 6), wa = ra & 63;
    const unsigned short* aBase = xq + ((size_t)(n * 66 + ha) * 66 + wa) * 256;
    const unsigned short* bBase = wq + (size_t)rb * 256;
    unsigned short* lAw0 = lA + ra * 64 + (((sa)     ^ (ra & 7)) * 8);
    unsigned short* lAw1 = lA + ra * 64 + (((sa + 1) ^ (ra & 7)) * 8);
    unsigned short* lBw0 = lB + rb * 64 + (((sb)     ^ (rb & 7)) * 8);
    unsigned short* lBw1 = lB + rb * 64 + (((sb + 1) ^ (rb & 7)) * 8);
    unsigned short* lBw2 = lB + rb * 64 + (((sb + 2) ^ (rb & 7)) * 8);
    unsigned short* lBw3 = lB + rb * 64 + (((sb + 3) ^ (rb & 7)) * 8);

    f32x16 acc[2][2] = {};
    int arow0 = wm * 64 + l31, arow1 = arow0 + 32;
    int brow0 = wn * 64 + l31, brow1 = brow0 + 32;

    for (int tap = 0; tap < 9; ++tap) {
        const unsigned short* aTap = aBase + ((tap / 3) * 66 + (tap % 3)) * 256;
        const unsigned short* bTap = bBase + tap * 65536;
        for (int kc = 0; kc < 4; ++kc) {
            const unsigned short* aSrc = aTap + kc * 64;
            const unsigned short* bSrc = bTap + kc * 64;
            uint4 va0 = *(const uint4*)(aSrc + sa * 8);
            uint4 va1 = *(const uint4*)(aSrc + sa * 8 + 8);
            uint4 vb0 = *(const uint4*)(bSrc + sb * 8);
            uint4 vb1 = *(const uint4*)(bSrc + sb * 8 + 8);
            uint4 vb2 = *(const uint4*)(bSrc + sb * 8 + 16);
            uint4 vb3 = *(const uint4*)(bSrc + sb * 8 + 24);
            __syncthreads();                       // prev compute done
            *(uint4*)lAw0 = va0; *(uint4*)lAw1 = va1;
            *(uint4*)lBw0 = vb0; *(uint4*)lBw1 = vb1;
            *(uint4*)lBw2 = vb2; *(uint4*)lBw3 = vb3;
            __syncthreads();                       // writes visible
#pragma unroll
            for (int ks = 0; ks < 4; ++ks) {       // K=16 per mfma
                int sl = ks * 2 + l5;
                short8 af0 = *(const short8*)(lA + arow0 * 64 + ((sl ^ (arow0 & 7)) * 8));
                short8 af1 = *(const short8*)(lA + arow1 * 64 + ((sl ^ (arow1 & 7)) * 8));
                short8 bf0 = *(const short8*)(lB + brow0 * 64 + ((sl ^ (brow0 & 7)) * 8));
                short8 bf1 = *(const short8*)(lB + brow1 * 64 + ((sl ^ (brow1 & 7)) * 8));
                acc[0][0] = __builtin_amdgcn_mfma_f32_32x32x16_bf16(af0, bf0, acc[0][0], 0, 0, 0);
                acc[0][1] = __builtin_amdgcn_mfma_f32_32x32x16_bf16(af0, bf1, acc[0][1], 0, 0, 0);
                acc[1][0] = __builtin_amdgcn_mfma_f32_32x32x16_bf16(af1, bf0, acc[1][0], 0, 0, 0);
                acc[1][1] = __builtin_amdgcn_mfma_f32_32x32x16_bf16(af1, bf1, acc[1][1], 0, 0, 0);
            }
        }
    }

    // epilogue: D layout col = l&31, row = (r&3) + 8*(r>>2) + 4*(l>>5)
    float qs = sc[2];
    float bv0 = bias[brow0], bv1 = bias[brow1];
    int hrow = h0 + wm;
#pragma unroll
    for (int mf = 0; mf < 2; ++mf) {
#pragma unroll
        for (int nf = 0; nf < 2; ++nf) {
            int co = nf ? brow1 : brow0;
            float bv = nf ? bv1 : bv0;
            float* ob = out + ((size_t)(n * 256 + co) * 4096) + hrow * 64 + mf * 32 + l5 * 4;
#pragma unroll
            for (int rg = 0; rg < 4; ++rg) {
                float4 v;
                v.x = acc[mf][nf][rg * 4 + 0] * qs + bv;
                v.y = acc[mf][nf][rg * 4 + 1] * qs + bv;
                v.z = acc[mf][nf][rg * 4 + 2] * qs + bv;
                v.w = acc[mf][nf][rg * 4 + 3] * qs + bv;
                *(float4*)(ob + rg * 8) = v;
            }
        }
    }
}

extern "C" void kernel_launch(void* const* d_in, const int* in_sizes, int n_in,
                              void* d_out, int out_size, void* d_ws, size_t ws_size,
                              hipStream_t stream) {
    (void)in_sizes; (void)n_in; (void)out_size; (void)ws_size;
    const float* x    = (const float*)d_in[0];
    const float* wgt  = (const float*)d_in[1];
    const float* bias = (const float*)d_in[2];
    const float* lnw  = (const float*)d_in[3];
    const float* lnb  = (const float*)d_in[4];
    float* out = (float*)d_out;
    char* ws = (char*)d_ws;

    unsigned short* xq = (unsigned short*)ws;
    unsigned short* wq = (unsigned short*)(ws + WQ_OFF);
    double2* gnp = (double2*)(ws + GNP_OFF);
    float2*  mr  = (float2*)(ws + MR_OFF);
    float*   gp  = (float*)(ws + GP_OFF);
    float*   sc  = (float*)(ws + SC_OFF);
    double*  wp  = (double*)(ws + WP_OFF);
    float*   dl  = (float*)(ws + DL_OFF);

    hipMemsetAsync(xq, 0, XQ_BYTES, stream);                 // zero halo (whole buffer)
    k_gn_part <<<1024, 256, 0, stream>>>(x, gnp);
    k_gn_final<<<16,   64,  0, stream>>>(gnp, mr);
    k_absmax  <<<1024, 256, 0, stream>>>(x, mr, lnw, lnb, gp);
    k_gamma   <<<1,    256, 0, stream>>>(gp, sc);
    k_wsum    <<<36,   256, 0, stream>>>(wgt, wp);
    k_wdelta  <<<1,    64,  0, stream>>>(wp, dl);
    k_wquant  <<<2304, 256, 0, stream>>>(wgt, dl, wq);
    k_quantx  <<<1024, 256, 0, stream>>>(x, mr, sc, lnw, lnb, xq);
    k_conv    <<<512,  512, 0, stream>>>(xq, wq, sc, bias, out);
}

// Round 2
// 141.867 us; speedup vs baseline: 1.1150x; 1.1150x over previous
//
#include <hip/hip_runtime.h>
#include <hip/hip_bf16.h>

// ---------------- problem constants ----------------
#define CHW   1048576        // 256*64*64
// ws layout (bytes)
#define XQ_BYTES 35684352u   // 16*66*66*256*2
#define WQ_OFF   35684352u   // 9*256*256*2 = 1179648
#define GNP_OFF  36864000u   // double2[1024]
#define CMM_OFF  36880384u   // float2[4096]
#define MR_OFF   36913152u   // float2[16]
#define SC_OFF   36913280u   // float[4]
#define WP_OFF   36913296u   // double[36]
#define DL_OFF   36913584u   // float delta

typedef __attribute__((ext_vector_type(8)))  short short8;
typedef __attribute__((ext_vector_type(16))) float f32x16;

__device__ __forceinline__ unsigned short f2bf(float f) {
    __hip_bfloat16 h = __float2bfloat16(f);
    return __builtin_bit_cast(unsigned short, h);
}

__device__ __forceinline__ void gload16(const void* g, void* l) {
    __builtin_amdgcn_global_load_lds(
        (const __attribute__((address_space(1))) unsigned int*)(unsigned long long)(g),
        (__attribute__((address_space(3))) unsigned int*)(unsigned int)(unsigned long long)(l),
        16, 0, 0);
}

// ---------- K1: fused per-sample sum/sumsq + per-(n,c) min/max (grid 1024, block 256) ----------
__global__ void k_pass1(const float* __restrict__ x, double2* __restrict__ part,
                        float2* __restrict__ cmm) {
    int bid = blockIdx.x;
    int n = bid >> 6, c4 = bid & 63;
    int t = threadIdx.x, ch = t >> 6, lane = t & 63;
    int c = c4 * 4 + ch;
    const float4* p = (const float4*)(x + (size_t)n * CHW + (size_t)c * 4096);
    double s = 0.0, ss = 0.0;
    float mn = 1e30f, mx = -1e30f;
#pragma unroll
    for (int k = 0; k < 16; ++k) {
        float4 v = p[k * 64 + lane];
        mn = fminf(mn, fminf(fminf(v.x, v.y), fminf(v.z, v.w)));
        mx = fmaxf(mx, fmaxf(fmaxf(v.x, v.y), fmaxf(v.z, v.w)));
        double dx = v.x, dy = v.y, dz = v.z, dw = v.w;
        s  += dx + dy + dz + dw;
        ss += dx * dx + dy * dy + dz * dz + dw * dw;
    }
    for (int o = 32; o; o >>= 1) {
        s += __shfl_down(s, o); ss += __shfl_down(ss, o);
        mn = fminf(mn, __shfl_down(mn, o)); mx = fmaxf(mx, __shfl_down(mx, o));
    }
    __shared__ double sh0[4], sh1[4];
    if (lane == 0) {
        cmm[n * 256 + c] = make_float2(mn, mx);
        sh0[ch] = s; sh1[ch] = ss;
    }
    __syncthreads();
    if (t == 0)
        part[bid] = make_double2(sh0[0] + sh0[1] + sh0[2] + sh0[3],
                                 sh1[0] + sh1[1] + sh1[2] + sh1[3]);
}

// ---------- K2: partial sum |W| (grid 36, block 256) ----------
__global__ void k_wsum(const float* __restrict__ w, double* __restrict__ wp) {
    int blk = blockIdx.x, t = threadIdx.x;
    const float4* p = (const float4*)(w + (size_t)blk * 16384);
    double s = 0.0;
#pragma unroll
    for (int j = 0; j < 16; ++j) {
        float4 v = p[j * 256 + t];
        s += fabs((double)v.x) + fabs((double)v.y) + fabs((double)v.z) + fabs((double)v.w);
    }
    for (int o = 32; o; o >>= 1) s += __shfl_down(s, o);
    __shared__ double sh[4];
    if ((t & 63) == 0) sh[t >> 6] = s;
    __syncthreads();
    if (t == 0) wp[blk] = sh[0] + sh[1] + sh[2] + sh[3];
}

// ---------- K3: all scalar reductions in one block ----------
__global__ void k_scalars(const double2* __restrict__ part, const float2* __restrict__ cmm,
                          const float* __restrict__ lnw, const float* __restrict__ lnb,
                          const double* __restrict__ wp,
                          float2* __restrict__ mr, float* __restrict__ sc,
                          float* __restrict__ dl) {
    __shared__ float shm[16], shr[16];
    int t = threadIdx.x;                 // 256
    {   // mean / rstd: t = n*16 + i
        int n = t >> 4, i = t & 15;
        double s = 0.0, ss = 0.0;
#pragma unroll
        for (int k = 0; k < 4; ++k) {
            double2 v = part[n * 64 + i * 4 + k];
            s += v.x; ss += v.y;
        }
        for (int o = 8; o; o >>= 1) { s += __shfl_down(s, o); ss += __shfl_down(ss, o); }
        if (i == 0) {
            double mean = s * (1.0 / 1048576.0);
            double var  = ss * (1.0 / 1048576.0) - mean * mean;
            shm[n] = (float)mean; shr[n] = (float)(1.0 / sqrt(var + 1e-5));
        }
    }
    __syncthreads();
    if (t < 16) mr[t] = make_float2(shm[t], shr[t]);
    // gamma from per-channel min/max (affine endpoints)
    float m = 0.0f;
#pragma unroll
    for (int k = 0; k < 16; ++k) {
        int idx = t + k * 256;
        int n = idx >> 8, c = idx & 255;
        float2 v = cmm[idx];
        float scale = lnw[c] * shr[n];
        float shift = lnb[c] - shm[n] * scale;
        m = fmaxf(m, fmaxf(fabsf(v.x * scale + shift), fabsf(v.y * scale + shift)));
    }
    for (int o = 32; o; o >>= 1) m = fmaxf(m, __shfl_down(m, o));
    __shared__ float shg[4];
    if ((t & 63) == 0) shg[t >> 6] = m;
    __syncthreads();
    if (t == 0) {
        float gamma = fmaxf(fmaxf(fmaxf(shg[0], shg[1]), fmaxf(shg[2], shg[3])), 1e-6f);
        sc[0] = gamma;
        sc[1] = 128.0f / gamma;
        sc[2] = (gamma / 128.0f) * 0.01f;
    }
    // delta
    if (t < 64) {
        double s = (t < 36) ? wp[t] : 0.0;
        for (int o = 32; o; o >>= 1) s += __shfl_down(s, o);
        if (t == 0) dl[0] = (float)(0.7 * (s / 589824.0));
    }
}

// ---------- K4: ternary quantize W -> wq[tap][co][ci] bf16 sign (grid 2304, block 256) ----------
__global__ void k_wquant(const float* __restrict__ w, const float* __restrict__ dl,
                         unsigned short* __restrict__ wq) {
    int o = blockIdx.x * 256 + threadIdx.x;   // tap*65536 + co*256 + ci
    int tap = o >> 16, rem = o & 65535, co = rem >> 8, ci = rem & 255;
    float d = dl[0];
    float v = w[co * 2304 + ci * 9 + tap];
    float s = (v > d) ? 1.0f : ((v < -d) ? -1.0f : 0.0f);
    wq[o] = f2bf(s);
}

// ---------- K5: zero only the halo of xq (grid 520, block 256) ----------
__global__ void k_halo(unsigned short* __restrict__ xq) {
    int idx = blockIdx.x * 8 + (threadIdx.x >> 5);   // 0..4159
    int n = idx / 260, p = idx - n * 260;
    int hh, ww;
    if (p < 66)       { hh = 0;        ww = p; }
    else if (p < 132) { hh = 65;       ww = p - 66; }
    else if (p < 196) { hh = p - 131;  ww = 0; }
    else              { hh = p - 195;  ww = 65; }
    uint4 z = make_uint4(0, 0, 0, 0);
    *(uint4*)(xq + ((size_t)(n * 66 + hh) * 66 + ww) * 256 + (threadIdx.x & 31) * 8) = z;
}

// ---------- K6: GN + quantize + NCHW -> padded NHWC bf16 (grid 1024, block 256) ----------
__global__ void k_quantx(const float* __restrict__ x, const float2* __restrict__ mr,
                         const float* __restrict__ sc, const float* __restrict__ lnw,
                         const float* __restrict__ lnb, unsigned short* __restrict__ xq) {
    int bid = blockIdx.x;
    int n = bid >> 6, hg = (bid >> 2) & 15, cg = bid & 3;
    int t = threadIdx.x;
    int w = t & 63, h = hg * 4 + (t >> 6);
    float2 m = mr[n];
    float s128 = sc[1];
    uint q[32];
    const float* xp = x + (((size_t)n * 256 + cg * 64) * 64 + h) * 64 + w;
#pragma unroll
    for (int ci = 0; ci < 64; ++ci) {
        int c = cg * 64 + ci;
        float g = lnw[c] * m.y;
        float be = lnb[c];
        float v = xp[(size_t)ci * 4096];
        float xs = ((v - m.x) * g + be) * s128;
        xs = fminf(fmaxf(xs, -(128.0f - 1e-6f)), (128.0f - 1e-6f));
        unsigned short ub = f2bf(rintf(xs));
        if (ci & 1) q[ci >> 1] |= ((uint)ub << 16);
        else        q[ci >> 1]  = ub;
    }
    unsigned short* op = xq + ((size_t)(n * 66 + h + 1) * 66 + (w + 1)) * 256 + cg * 64;
    uint4* o4 = (uint4*)op;
#pragma unroll
    for (int s2 = 0; s2 < 8; ++s2)
        o4[s2] = make_uint4(q[s2 * 4], q[s2 * 4 + 1], q[s2 * 4 + 2], q[s2 * 4 + 3]);
}

// ---------- K7: conv as 9-tap implicit GEMM, pipelined (tri-buffer, counted vmcnt) ----------
// grid 256 (16 n x 16 h-quads), 512 thr (8 waves 2m x 4n), tile 256(sp) x 256(co), BK=32
#define LDSB 16384   // shorts per buffer (A 8192 + B 8192)

#define MFMA8(A0,A1,A2,A3,B0,B1) \
    acc[0][0] = __builtin_amdgcn_mfma_f32_32x32x16_bf16(A0, B0, acc[0][0], 0, 0, 0); \
    acc[0][1] = __builtin_amdgcn_mfma_f32_32x32x16_bf16(A0, B1, acc[0][1], 0, 0, 0); \
    acc[1][0] = __builtin_amdgcn_mfma_f32_32x32x16_bf16(A1, B0, acc[1][0], 0, 0, 0); \
    acc[1][1] = __builtin_amdgcn_mfma_f32_32x32x16_bf16(A1, B1, acc[1][1], 0, 0, 0); \
    acc[2][0] = __builtin_amdgcn_mfma_f32_32x32x16_bf16(A2, B0, acc[2][0], 0, 0, 0); \
    acc[2][1] = __builtin_amdgcn_mfma_f32_32x32x16_bf16(A2, B1, acc[2][1], 0, 0, 0); \
    acc[3][0] = __builtin_amdgcn_mfma_f32_32x32x16_bf16(A3, B0, acc[3][0], 0, 0, 0); \
    acc[3][1] = __builtin_amdgcn_mfma_f32_32x32x16_bf16(A3, B1, acc[3][1], 0, 0, 0);

#define LD8(off) (*(const short8*)&lds[(off)])

// one chunk: 2 phases (ks=0,1); stages chunk CC+2 into SBUF; WAITM: 4 / 0 / -1
#define CHUNK(BUF, CC, SBUF, DOSTAGE, WAITM) { \
    const int _bo = (BUF) * LDSB; \
    { /* phase 0 */ \
        short8 a0 = LD8(_bo + rdA0 + p0), a1 = LD8(_bo + rdA1 + p0); \
        short8 a2 = LD8(_bo + rdA2 + p0), a3 = LD8(_bo + rdA3 + p0); \
        short8 b0 = LD8(_bo + rdB0 + p0), b1 = LD8(_bo + rdB1 + p0); \
        if (DOSTAGE) { \
            int _c2 = (CC) + 2, _tap = _c2 >> 3, _kc = _c2 & 7; \
            int _aAdd = ((_tap / 3) * 66 + (_tap % 3)) * 256 + _kc * 32; \
            gload16(xq + aOff0 + _aAdd, &lds[(SBUF) * LDSB + dA0]); \
            gload16(xq + aOff1 + _aAdd, &lds[(SBUF) * LDSB + dA1]); \
        } \
        __builtin_amdgcn_s_barrier(); \
        __builtin_amdgcn_s_setprio(1); \
        MFMA8(a0, a1, a2, a3, b0, b1) \
        __builtin_amdgcn_s_setprio(0); \
        __builtin_amdgcn_s_barrier(); \
    } \
    { /* phase 1 */ \
        short8 a0 = LD8(_bo + rdA0 + p1), a1 = LD8(_bo + rdA1 + p1); \
        short8 a2 = LD8(_bo + rdA2 + p1), a3 = LD8(_bo + rdA3 + p1); \
        short8 b0 = LD8(_bo + rdB0 + p1), b1 = LD8(_bo + rdB1 + p1); \
        if (DOSTAGE) { \
            int _c2 = (CC) + 2, _tap = _c2 >> 3, _kc = _c2 & 7; \
            int _bAdd = _tap * 65536 + _kc * 32; \
            gload16(wq + bOff0 + _bAdd, &lds[(SBUF) * LDSB + dB0]); \
            gload16(wq + bOff1 + _bAdd, &lds[(SBUF) * LDSB + dB1]); \
        } \
        __builtin_amdgcn_s_barrier(); \
        __builtin_amdgcn_s_setprio(1); \
        MFMA8(a0, a1, a2, a3, b0, b1) \
        __builtin_amdgcn_s_setprio(0); \
        if ((WAITM) == 4)      asm volatile("s_waitcnt vmcnt(4)" ::: "memory"); \
        else if ((WAITM) == 0) asm volatile("s_waitcnt vmcnt(0)" ::: "memory"); \
        __builtin_amdgcn_s_barrier(); \
    } \
}

__global__ __launch_bounds__(512, 2) void k_conv(const unsigned short* __restrict__ xq,
                                                 const unsigned short* __restrict__ wq,
                                                 const float* __restrict__ sc,
                                                 const float* __restrict__ bias,
                                                 float* __restrict__ out) {
    __shared__ unsigned short lds[3 * LDSB];   // 96 KB
    int bid = blockIdx.x;
    int n = bid >> 4, h0 = (bid & 15) << 2;
    int t = threadIdx.x, wv = t >> 6, l = t & 63;
    int wm = wv >> 2, wn = wv & 3;
    int l31 = l & 31, l5 = l >> 5;

    // ----- staging constants (per thread) -----
    int lr = l >> 2;                        // 0..15 : row within a 16-row wave-load
    int g  = (l & 3) ^ (lr & 3);            // source k-slot (involution with read swizzle)
    int rA0 = wv * 32 + lr, rA1 = rA0 + 16; // rows 0..255
    int aOff0 = ((n * 66 + h0 + (rA0 >> 6)) * 66 + (rA0 & 63)) * 256 + g * 8;
    int aOff1 = ((n * 66 + h0 + (rA1 >> 6)) * 66 + (rA1 & 63)) * 256 + g * 8;
    int bOff0 = rA0 * 256 + g * 8;
    int bOff1 = rA1 * 256 + g * 8;
    int dA0 = wv * 1024,        dA1 = wv * 1024 + 512;         // LDS elem offsets in buffer
    int dB0 = 8192 + wv * 1024, dB1 = 8192 + wv * 1024 + 512;

    // ----- read constants -----
    int q  = l31 & 3;
    int p0 = ((0 + l5) ^ q) * 8;            // ks=0 slot (elements)
    int p1 = ((2 + l5) ^ q) * 8;            // ks=1 slot
    int rdA0 = (wm * 128 +   0 + l31) * 32;
    int rdA1 = (wm * 128 +  32 + l31) * 32;
    int rdA2 = (wm * 128 +  64 + l31) * 32;
    int rdA3 = (wm * 128 +  96 + l31) * 32;
    int rdB0 = 8192 + (wn * 64 +  0 + l31) * 32;
    int rdB1 = 8192 + (wn * 64 + 32 + l31) * 32;

    f32x16 acc[4][2] = {};

    // ----- prologue: stage chunks 0 (buf0) and 1 (buf1) -----
    {
        gload16(xq + aOff0, &lds[dA0]);
        gload16(xq + aOff1, &lds[dA1]);
        gload16(wq + bOff0, &lds[dB0]);
        gload16(wq + bOff1, &lds[dB1]);
        int _aAdd = 32, _bAdd = 32;   // chunk 1: tap 0, kc 1
        gload16(xq + aOff0 + _aAdd, &lds[LDSB + dA0]);
        gload16(xq + aOff1 + _aAdd, &lds[LDSB + dA1]);
        gload16(wq + bOff0 + _bAdd, &lds[LDSB + dB0]);
        gload16(wq + bOff1 + _bAdd, &lds[LDSB + dB1]);
    }
    asm volatile("s_waitcnt vmcnt(4)" ::: "memory");
    __builtin_amdgcn_s_barrier();

    // ----- main loop: chunks 0..68 (23 x 3), staging c+2 -----
    int c = 0;
#pragma unroll 1
    for (int it = 0; it < 23; ++it) {
        CHUNK(0, c,     2, true, 4)
        CHUNK(1, c + 1, 0, true, 4)
        CHUNK(2, c + 2, 1, true, 4)
        c += 3;
    }
    CHUNK(0, 69, 2, true, 4)       // stages chunk 71 -> buf 2
    CHUNK(1, 70, 0, false, 0)      // drain: chunk 71 must be resident
    CHUNK(2, 71, 0, false, -1)

    // ----- epilogue -----
    float qs = sc[2];
    int hb = h0 + wm * 2;
#pragma unroll
    for (int mf = 0; mf < 4; ++mf) {
        int h = hb + (mf >> 1);
        int wb = (mf & 1) * 32 + l5 * 4;
#pragma unroll
        for (int nf = 0; nf < 2; ++nf) {
            int co = wn * 64 + nf * 32 + l31;
            float bv = bias[co];
            float* ob = out + ((size_t)(n * 256 + co) * 4096) + h * 64 + wb;
#pragma unroll
            for (int rg = 0; rg < 4; ++rg) {
                float4 v;
                v.x = acc[mf][nf][rg * 4 + 0] * qs + bv;
                v.y = acc[mf][nf][rg * 4 + 1] * qs + bv;
                v.z = acc[mf][nf][rg * 4 + 2] * qs + bv;
                v.w = acc[mf][nf][rg * 4 + 3] * qs + bv;
                *(float4*)(ob + rg * 8) = v;
            }
        }
    }
}

extern "C" void kernel_launch(void* const* d_in, const int* in_sizes, int n_in,
                              void* d_out, int out_size, void* d_ws, size_t ws_size,
                              hipStream_t stream) {
    (void)in_sizes; (void)n_in; (void)out_size; (void)ws_size;
    const float* x    = (const float*)d_in[0];
    const float* wgt  = (const float*)d_in[1];
    const float* bias = (const float*)d_in[2];
    const float* lnw  = (const float*)d_in[3];
    const float* lnb  = (const float*)d_in[4];
    float* out = (float*)d_out;
    char* ws = (char*)d_ws;

    unsigned short* xq = (unsigned short*)ws;
    unsigned short* wq = (unsigned short*)(ws + WQ_OFF);
    double2* gnp = (double2*)(ws + GNP_OFF);
    float2*  cmm = (float2*)(ws + CMM_OFF);
    float2*  mr  = (float2*)(ws + MR_OFF);
    float*   sc  = (float*)(ws + SC_OFF);
    double*  wp  = (double*)(ws + WP_OFF);
    float*   dl  = (float*)(ws + DL_OFF);

    k_pass1  <<<1024, 256, 0, stream>>>(x, gnp, cmm);
    k_wsum   <<<36,   256, 0, stream>>>(wgt, wp);
    k_scalars<<<1,    256, 0, stream>>>(gnp, cmm, lnw, lnb, wp, mr, sc, dl);
    k_wquant <<<2304, 256, 0, stream>>>(wgt, dl, wq);
    k_halo   <<<520,  256, 0, stream>>>(xq);
    k_quantx <<<1024, 256, 0, stream>>>(x, mr, sc, lnw, lnb, xq);
    k_conv   <<<256,  512, 0, stream>>>(xq, wq, sc, bias, out);
}